// Round 1
// baseline (855.974 us; speedup 1.0000x reference)
//
#include <hip/hip_runtime.h>
#include <math.h>

#define CIN 4
#define F_ 16
#define NTAP 125
#define NMAP 16
#define NVOX 48

// ---------------------------------------------------------------------------
// Kernel 1: build effective filters EF[c][tap][g][f][m4]  (g*4+m4 = map, 16 maps)
// map order: (0,0,re) | (1,0,re),(1,1,re),(1,1,im) | (2,0..2 re/im) | (3,0..3 re/im)
// Folds: radial shells, degree-shared w, and sqrt((m>0?2:1)/(2n+1)) power scale.
// ---------------------------------------------------------------------------
__global__ void build_filters(const float* __restrict__ w, float* __restrict__ ef) {
    int idx = blockIdx.x * 256 + threadIdx.x;
    if (idx >= CIN * NTAP * NMAP * F_) return;  // 128000
    int m4 = idx & 3;
    int f = (idx >> 2) & 15;
    int g = (idx >> 6) & 3;
    int rest = idx >> 8;          // c*125 + tap
    int tap = rest % 125;
    int c = rest / 125;
    int map = g * 4 + m4;

    int fd = tap / 25, fh = (tap / 5) % 5, fw = tap % 5;
    // meshgrid(indexing='xy'): x = g[fh], y = g[fd], z = g[fw]
    float xx = (float)(fh - 2), yy = (float)(fd - 2), zz = (float)(fw - 2);
    float r = sqrtf(xx * xx + yy * yy + zz * zz);
    float rxy = sqrtf(xx * xx + yy * yy);
    float ct = (r > 0.f) ? zz / r : 0.f;                 // arccos(z/r), 0 at r=0
    float st = sqrtf(fmaxf(0.f, 1.f - ct * ct));
    float cp = (rxy > 0.f) ? xx / rxy : 1.f;             // cos(atan2(y,x))
    float sp = (rxy > 0.f) ? yy / rxy : 0.f;
    float c2p = cp * cp - sp * sp, s2p = 2.f * cp * sp;
    float c3p = c2p * cp - s2p * sp, s3p = s2p * cp + c2p * sp;

    const float k00 = 0.28209479177387814f;
    const float k10 = 0.48860251190291992f;
    const float c1v = 0.34549414947133547f;
    const float k20 = 0.31539156525252005f;
    const float c21 = 0.77254840404637908f;
    const float c22 = 0.38627420202318954f;
    const float k30 = 0.37317633259011546f;
    const float c31 = 0.32318018411415065f;
    const float c32 = 1.02198547643328236f;
    const float c33 = 0.41722382363278409f;

    float val;
    int deg;
    switch (map) {
        case 0:  deg = 0; val = k00; break;
        case 1:  deg = 1; val = k10 * ct; break;
        case 2:  deg = 1; val = -c1v * st * cp; break;
        case 3:  deg = 1; val = -c1v * st * sp; break;
        case 4:  deg = 2; val = k20 * (3.f * ct * ct - 1.f); break;
        case 5:  deg = 2; val = -c21 * st * ct * cp; break;
        case 6:  deg = 2; val = -c21 * st * ct * sp; break;
        case 7:  deg = 2; val = c22 * st * st * c2p; break;
        case 8:  deg = 2; val = c22 * st * st * s2p; break;
        case 9:  deg = 3; val = k30 * (5.f * ct * ct * ct - 3.f * ct); break;
        case 10: deg = 3; val = -c31 * st * (5.f * ct * ct - 1.f) * cp; break;
        case 11: deg = 3; val = -c31 * st * (5.f * ct * ct - 1.f) * sp; break;
        case 12: deg = 3; val = c32 * st * st * ct * c2p; break;
        case 13: deg = 3; val = c32 * st * st * ct * s2p; break;
        case 14: deg = 3; val = -c33 * st * st * st * c3p; break;
        default: deg = 3; val = -c33 * st * st * st * s3p; break;
    }
    // sqrt(((m>0)?2:1)/(2n+1)) per map
    const float scale_tab[16] = {
        1.f,
        0.57735026918962576f, 0.81649658092772603f, 0.81649658092772603f,
        0.44721359549995794f, 0.63245553203367587f, 0.63245553203367587f,
        0.63245553203367587f, 0.63245553203367587f,
        0.37796447300922720f, 0.53452248382484879f, 0.53452248382484879f,
        0.53452248382484879f, 0.53452248382484879f, 0.53452248382484879f,
        0.53452248382484879f};

    float wsum = 0.f;
#pragma unroll
    for (int i = 0; i < 3; ++i) {
        float rad = fmaxf(0.f, 1.f - fabsf(r - (float)i));  // clip(1-|r-i|,0,1)
        wsum += rad * w[((c * F_ + f) * 3 + i) * 4 + deg];
    }
    ef[idx] = wsum * val * scale_tab[map];
}

// ---------------------------------------------------------------------------
// Kernel 2: main fused kernel.
// Block = 256 threads = 16 f-lanes x 16 voxel-groups; 4x4x4 spatial tile;
// each thread accumulates 4 voxels (along d) x 16 maps for one f.
// ---------------------------------------------------------------------------
__global__ __launch_bounds__(256) void sshconv_main(
    const float* __restrict__ x, const float* __restrict__ ef,
    const float* __restrict__ w_cp, const float* __restrict__ b_cp,
    const float* __restrict__ bias, const float* __restrict__ w_proj,
    const float* __restrict__ b_proj, float* __restrict__ out) {
    __shared__ float4 xs[512];       // 8x8x8 voxels, float4 = 4 channels (8 KB)
    __shared__ float s_lds[64][65];  // 64 voxels x 64 (f*4+n) values, padded

    const int tid = threadIdx.x;
    const int bt = blockIdx.x;
    const int tw = bt % 12, th = (bt / 12) % 12, td = (bt / 144) % 12, b = bt / 1728;
    const int d0 = td * 4, h0 = th * 4, w0 = tw * 4;

    // ---- stage x tile (with zero halo) ----
#pragma unroll
    for (int i = 0; i < 2; ++i) {
        int s = tid * 2 + i;  // 0..511
        int sd = s >> 6, sh = (s >> 3) & 7, sw = s & 7;
        int gd = d0 - 2 + sd, gh = h0 - 2 + sh, gw = w0 - 2 + sw;
        float4 v = make_float4(0.f, 0.f, 0.f, 0.f);
        if (gd >= 0 && gd < NVOX && gh >= 0 && gh < NVOX && gw >= 0 && gw < NVOX)
            v = *(const float4*)&x[(((b * NVOX + gd) * NVOX + gh) * NVOX + gw) * CIN];
        xs[s] = v;
    }
    __syncthreads();

    const int f = tid & 15, vg = tid >> 4;
    const int lh = vg >> 2, lw = vg & 3;

    float acc[4][16];
#pragma unroll
    for (int j = 0; j < 4; ++j)
#pragma unroll
        for (int m = 0; m < 16; ++m) acc[j][m] = 0.f;

    const int efbase_f = f * 4;

    for (int fd = 0; fd < 5; ++fd) {
        for (int fh = 0; fh < 5; ++fh) {
#pragma unroll
            for (int fw5 = 0; fw5 < 5; ++fw5) {
                const int tap = (fd * 5 + fh) * 5 + fw5;
                const int xb = fd * 64 + (lh + fh) * 8 + (lw + fw5);
                float4 xv[4];
#pragma unroll
                for (int j = 0; j < 4; ++j) xv[j] = xs[xb + j * 64];
#pragma unroll
                for (int c = 0; c < 4; ++c) {
                    const float* efp = ef + (c * 125 + tap) * 256 + efbase_f;
                    float4 f0 = *(const float4*)(efp);
                    float4 f1 = *(const float4*)(efp + 64);
                    float4 f2 = *(const float4*)(efp + 128);
                    float4 f3 = *(const float4*)(efp + 192);
#pragma unroll
                    for (int j = 0; j < 4; ++j) {
                        float xvc = (c == 0) ? xv[j].x : (c == 1) ? xv[j].y
                                   : (c == 2) ? xv[j].z : xv[j].w;
                        acc[j][0]  += xvc * f0.x;  acc[j][1]  += xvc * f0.y;
                        acc[j][2]  += xvc * f0.z;  acc[j][3]  += xvc * f0.w;
                        acc[j][4]  += xvc * f1.x;  acc[j][5]  += xvc * f1.y;
                        acc[j][6]  += xvc * f1.z;  acc[j][7]  += xvc * f1.w;
                        acc[j][8]  += xvc * f2.x;  acc[j][9]  += xvc * f2.y;
                        acc[j][10] += xvc * f2.z;  acc[j][11] += xvc * f2.w;
                        acc[j][12] += xvc * f3.x;  acc[j][13] += xvc * f3.y;
                        acc[j][14] += xvc * f3.z;  acc[j][15] += xvc * f3.w;
                    }
                }
            }
        }
    }

    // ---- central-pixel 1x1x1 conv added to map 0 (scale of (0,0) is 1) ----
#pragma unroll
    for (int j = 0; j < 4; ++j) {
        float4 xc = xs[(j + 2) * 64 + (lh + 2) * 8 + (lw + 2)];
        float cen = b_cp[f];
        cen += xc.x * w_cp[0 * F_ + f];
        cen += xc.y * w_cp[1 * F_ + f];
        cen += xc.z * w_cp[2 * F_ + f];
        cen += xc.w * w_cp[3 * F_ + f];
        acc[j][0] += cen;
    }

    // ---- power spectrum per degree (+bias, signed log1p) -> LDS ----
#pragma unroll
    for (int j = 0; j < 4; ++j) {
        const int vox = j * 16 + vg;  // ld*16 + lh*4 + lw
        float sv[4];
        sv[0] = acc[j][0] * acc[j][0];
        sv[1] = acc[j][1] * acc[j][1] + acc[j][2] * acc[j][2] + acc[j][3] * acc[j][3];
        sv[2] = acc[j][4] * acc[j][4] + acc[j][5] * acc[j][5] + acc[j][6] * acc[j][6] +
                acc[j][7] * acc[j][7] + acc[j][8] * acc[j][8];
        sv[3] = acc[j][9] * acc[j][9] + acc[j][10] * acc[j][10] + acc[j][11] * acc[j][11] +
                acc[j][12] * acc[j][12] + acc[j][13] * acc[j][13] + acc[j][14] * acc[j][14] +
                acc[j][15] * acc[j][15];
#pragma unroll
        for (int n = 0; n < 4; ++n) {
            float v = sv[n] + bias[f * 4 + n];
            float r_ = log1pf(fabsf(v));
            s_lds[vox][f * 4 + n] = copysignf(r_, v);
        }
    }
    __syncthreads();

    // ---- 64 -> 16 projection + relu + store ----
    const int fo = tid & 15, q = tid >> 4;
#pragma unroll
    for (int j = 0; j < 4; ++j) {
        const int vox = q * 4 + j;
        float o = b_proj[fo];
#pragma unroll 8
        for (int k = 0; k < 64; ++k) o += s_lds[vox][k] * w_proj[k * F_ + fo];
        o = fmaxf(o, 0.f);
        const int ld = vox >> 4, lhh = (vox >> 2) & 3, lww = vox & 3;
        out[(((b * NVOX + d0 + ld) * NVOX + h0 + lhh) * NVOX + w0 + lww) * F_ + fo] = o;
    }
}

extern "C" void kernel_launch(void* const* d_in, const int* in_sizes, int n_in,
                              void* d_out, int out_size, void* d_ws, size_t ws_size,
                              hipStream_t stream) {
    const float* x = (const float*)d_in[0];       // [2,48,48,48,4]
    const float* w = (const float*)d_in[1];       // [4,16,3,4]
    const float* w_cp = (const float*)d_in[2];    // [4,16]
    const float* b_cp = (const float*)d_in[3];    // [16]
    const float* bias = (const float*)d_in[4];    // [64]
    const float* w_proj = (const float*)d_in[5];  // [64,16]
    const float* b_proj = (const float*)d_in[6];  // [16]
    float* out = (float*)d_out;                   // [2,48,48,48,16]
    float* ef = (float*)d_ws;                     // 128000 floats (512 KB)

    build_filters<<<500, 256, 0, stream>>>(w, ef);
    sshconv_main<<<3456, 256, 0, stream>>>(x, ef, w_cp, b_cp, bias, w_proj, b_proj, out);
}

// Round 2
// 116.154 us; speedup vs baseline: 7.3693x; 7.3693x over previous
//
#include <hip/hip_runtime.h>
#include <math.h>

typedef _Float16 f16;
typedef _Float16 f16x4 __attribute__((ext_vector_type(4)));
typedef _Float16 f16x8 __attribute__((ext_vector_type(8)));
typedef float f32x4 __attribute__((ext_vector_type(4)));

#define NVOX 48
#define F_ 16

// ---------------------------------------------------------------------------
// Kernel 1: build effective filter bank directly in MFMA-B fragment layout.
// efb[kq(64)][n(256)][j(8)] f16, where K index k = kq*8+j = tap*4 + c,
// n = f*16 + map. Taps 125..127 are zero-pad. Folds radial shells, the
// degree-shared weights w, and sqrt((m>0?2:1)/(2n+1)) power-spectrum scale.
// ---------------------------------------------------------------------------
__global__ void build_filters(const float* __restrict__ w, f16* __restrict__ efb) {
    int e = blockIdx.x * 256 + threadIdx.x;  // 0..131071
    int j = e & 7;
    int n = (e >> 3) & 255;
    int kq = e >> 11;            // 0..63
    int k = kq * 8 + j;          // 0..511
    int tap = k >> 2, c = k & 3, f = n >> 4, map = n & 15;

    float outv = 0.f;
    if (tap < 125) {
        int fd = tap / 25, fh = (tap / 5) % 5, fw = tap % 5;
        // meshgrid(indexing='xy'): x = g[fh], y = g[fd], z = g[fw]
        float xx = (float)(fh - 2), yy = (float)(fd - 2), zz = (float)(fw - 2);
        float r = sqrtf(xx * xx + yy * yy + zz * zz);
        float rxy = sqrtf(xx * xx + yy * yy);
        float ct = (r > 0.f) ? zz / r : 0.f;
        float st = sqrtf(fmaxf(0.f, 1.f - ct * ct));
        float cp = (rxy > 0.f) ? xx / rxy : 1.f;
        float sp = (rxy > 0.f) ? yy / rxy : 0.f;
        float c2p = cp * cp - sp * sp, s2p = 2.f * cp * sp;
        float c3p = c2p * cp - s2p * sp, s3p = s2p * cp + c2p * sp;

        const float k00 = 0.28209479177387814f;
        const float k10 = 0.48860251190291992f;
        const float c1v = 0.34549414947133547f;
        const float k20 = 0.31539156525252005f;
        const float c21 = 0.77254840404637908f;
        const float c22 = 0.38627420202318954f;
        const float k30 = 0.37317633259011546f;
        const float c31 = 0.32318018411415065f;
        const float c32 = 1.02198547643328236f;
        const float c33 = 0.41722382363278409f;

        float val;
        int deg;
        switch (map) {
            case 0:  deg = 0; val = k00; break;
            case 1:  deg = 1; val = k10 * ct; break;
            case 2:  deg = 1; val = -c1v * st * cp; break;
            case 3:  deg = 1; val = -c1v * st * sp; break;
            case 4:  deg = 2; val = k20 * (3.f * ct * ct - 1.f); break;
            case 5:  deg = 2; val = -c21 * st * ct * cp; break;
            case 6:  deg = 2; val = -c21 * st * ct * sp; break;
            case 7:  deg = 2; val = c22 * st * st * c2p; break;
            case 8:  deg = 2; val = c22 * st * st * s2p; break;
            case 9:  deg = 3; val = k30 * (5.f * ct * ct * ct - 3.f * ct); break;
            case 10: deg = 3; val = -c31 * st * (5.f * ct * ct - 1.f) * cp; break;
            case 11: deg = 3; val = -c31 * st * (5.f * ct * ct - 1.f) * sp; break;
            case 12: deg = 3; val = c32 * st * st * ct * c2p; break;
            case 13: deg = 3; val = c32 * st * st * ct * s2p; break;
            case 14: deg = 3; val = -c33 * st * st * st * c3p; break;
            default: deg = 3; val = -c33 * st * st * st * s3p; break;
        }
        const float scale_tab[16] = {
            1.f,
            0.57735026918962576f, 0.81649658092772603f, 0.81649658092772603f,
            0.44721359549995794f, 0.63245553203367587f, 0.63245553203367587f,
            0.63245553203367587f, 0.63245553203367587f,
            0.37796447300922720f, 0.53452248382484879f, 0.53452248382484879f,
            0.53452248382484879f, 0.53452248382484879f, 0.53452248382484879f,
            0.53452248382484879f};

        float wsum = 0.f;
#pragma unroll
        for (int i = 0; i < 3; ++i) {
            float rad = fmaxf(0.f, 1.f - fabsf(r - (float)i));
            wsum += rad * w[((c * F_ + f) * 3 + i) * 4 + deg];
        }
        outv = wsum * val * scale_tab[map];
    }
    efb[e] = (f16)outv;
}

// ---------------------------------------------------------------------------
// Kernel 2: MFMA main kernel.
// Block = 256 threads = 4 waves. Tile: M=64 voxels (4x4x4), N=256 (16f x 16maps).
// Wave w owns n in [w*64, w*64+64). K = 512 (128 taps x 4 ch, taps >=125 zero).
// A-frag: lane holds voxel row (lane&15), taps kblk*8+(lane>>4)*2 +{0,1},
//          4 channels each -> two ds_read_b64 from xs tile.
// B-frag: one global_load_dwordx4 from efb (L2-resident).
// C-frag layout: col(n) = lane&15, row(voxel) = (lane>>4)*4 + reg.
// ---------------------------------------------------------------------------
__global__ __launch_bounds__(256) void sshconv_main(
    const float* __restrict__ x, const f16* __restrict__ efb,
    const float* __restrict__ w_cp, const float* __restrict__ b_cp,
    const float* __restrict__ bias, const float* __restrict__ w_proj,
    const float* __restrict__ b_proj, float* __restrict__ out) {
    __shared__ f16 xs[512 * 4];          // 8x8x8 voxels x 4ch fp16 (4 KB)
    __shared__ int off_tab[128];         // tap -> element offset in xs
    __shared__ float maps[32 * 289];     // 32 vox x (16f x 18pad) (37 KB)
    __shared__ float s_lds[32][65];      // 32 vox x 64 s-values (8.3 KB)

    const int tid = threadIdx.x;
    const int bt = blockIdx.x;
    const int tw = bt % 12, th = (bt / 12) % 12, td = (bt / 144) % 12, b = bt / 1728;
    const int d0 = td * 4, h0 = th * 4, w0 = tw * 4;

    // tap offset table (element index into 8x8x8 tile)
    if (tid < 128) {
        int t = tid;
        off_tab[t] = (t < 125) ? (t / 25) * 64 + ((t / 5) % 5) * 8 + (t % 5) : 0;
    }

    // stage x tile (zero halo), fp32 -> fp16
#pragma unroll
    for (int i = 0; i < 2; ++i) {
        int s = tid * 2 + i;  // 0..511
        int sd = s >> 6, sh = (s >> 3) & 7, sw = s & 7;
        int gd = d0 - 2 + sd, gh = h0 - 2 + sh, gw = w0 - 2 + sw;
        float4 v = make_float4(0.f, 0.f, 0.f, 0.f);
        if (gd >= 0 && gd < NVOX && gh >= 0 && gh < NVOX && gw >= 0 && gw < NVOX)
            v = *(const float4*)&x[(((b * NVOX + gd) * NVOX + gh) * NVOX + gw) * 4];
        f16x4 hv = {(f16)v.x, (f16)v.y, (f16)v.z, (f16)v.w};
        *(f16x4*)&xs[s * 4] = hv;
    }
    __syncthreads();

    const int lane = tid & 63, wv = tid >> 6;
    const int col = lane & 15, ksel = lane >> 4;   // ksel = K sub-group
    const int vh = col >> 2, vw = col & 3;         // A-row voxel (h,w) coords
    const int abase = vh * 8 + vw;                 // element base in xs

    f32x4 acc[4][4];  // [mf][nb]
#pragma unroll
    for (int m = 0; m < 4; ++m)
#pragma unroll
        for (int nbi = 0; nbi < 4; ++nbi) acc[m][nbi] = (f32x4){0.f, 0.f, 0.f, 0.f};

    // per-lane constant part of B address (f16 elements)
    const f16* bptr = efb + ((ksel * 256) + wv * 64 + col) * 8;

#pragma unroll 2
    for (int kblk = 0; kblk < 16; ++kblk) {
        const int t0 = kblk * 8 + ksel * 2;
        const int o0 = off_tab[t0], o1 = off_tab[t0 + 1];

        f16x8 a[4];
#pragma unroll
        for (int mf = 0; mf < 4; ++mf) {
            f16x4 lo = *(const f16x4*)&xs[(abase + mf * 64 + o0) * 4];
            f16x4 hi = *(const f16x4*)&xs[(abase + mf * 64 + o1) * 4];
            a[mf] = __builtin_shufflevector(lo, hi, 0, 1, 2, 3, 4, 5, 6, 7);
        }
        f16x8 bf[4];
#pragma unroll
        for (int nb = 0; nb < 4; ++nb)
            bf[nb] = *(const f16x8*)(bptr + kblk * 8192 + nb * 128);
#pragma unroll
        for (int nb = 0; nb < 4; ++nb)
#pragma unroll
            for (int mf = 0; mf < 4; ++mf)
                acc[mf][nb] = __builtin_amdgcn_mfma_f32_16x16x32_f16(
                    a[mf], bf[nb], acc[mf][nb], 0, 0, 0);
    }

    // ---- epilogue in two 32-voxel halves ----
    const int f = tid & 15;
    for (int h = 0; h < 2; ++h) {
        __syncthreads();
        // write maps: acc rows -> maps[vox32][f][map] (padded strides 289/18)
#pragma unroll
        for (int q = 0; q < 2; ++q) {
            const int mf = 2 * h + q;
#pragma unroll
            for (int nb = 0; nb < 4; ++nb) {
                const int fidx = wv * 4 + nb;
#pragma unroll
                for (int r = 0; r < 4; ++r) {
                    const int vox32 = q * 16 + ksel * 4 + r;
                    maps[vox32 * 289 + fidx * 18 + col] = acc[mf][nb][r];
                }
            }
        }
        __syncthreads();
        // spec + central + bias + signed log1p -> s_lds
#pragma unroll
        for (int p = 0; p < 2; ++p) {
            const int vox32 = (tid >> 4) + 16 * p;
            const float* mp = &maps[vox32 * 289 + f * 18];
            const int vg = h * 32 + vox32;
            const int vd = vg >> 4, vhh = (vg >> 2) & 3, vww = vg & 3;
            const f16* xc = &xs[(((vd + 2) * 64) + (vhh + 2) * 8 + (vww + 2)) * 4];
            float cen = b_cp[f];
            cen += (float)xc[0] * w_cp[0 * F_ + f];
            cen += (float)xc[1] * w_cp[1 * F_ + f];
            cen += (float)xc[2] * w_cp[2 * F_ + f];
            cen += (float)xc[3] * w_cp[3 * F_ + f];
            float m0 = mp[0] + cen;
            float sv[4];
            sv[0] = m0 * m0;
            sv[1] = mp[1] * mp[1] + mp[2] * mp[2] + mp[3] * mp[3];
            sv[2] = mp[4] * mp[4] + mp[5] * mp[5] + mp[6] * mp[6] +
                    mp[7] * mp[7] + mp[8] * mp[8];
            sv[3] = mp[9] * mp[9] + mp[10] * mp[10] + mp[11] * mp[11] +
                    mp[12] * mp[12] + mp[13] * mp[13] + mp[14] * mp[14] +
                    mp[15] * mp[15];
#pragma unroll
            for (int n = 0; n < 4; ++n) {
                float v = sv[n] + bias[f * 4 + n];
                s_lds[vox32][f * 4 + n] = copysignf(log1pf(fabsf(v)), v);
            }
        }
        __syncthreads();
        // 64 -> 16 projection + relu + store
#pragma unroll
        for (int p = 0; p < 2; ++p) {
            const int vox32 = (tid >> 4) + 16 * p;
            const int fo = tid & 15;
            float o = b_proj[fo];
#pragma unroll 8
            for (int kk = 0; kk < 64; ++kk) o += s_lds[vox32][kk] * w_proj[kk * F_ + fo];
            o = fmaxf(o, 0.f);
            const int vg = h * 32 + vox32;
            const int vd = vg >> 4, vhh = (vg >> 2) & 3, vww = vg & 3;
            out[(((b * NVOX + d0 + vd) * NVOX + h0 + vhh) * NVOX + w0 + vww) * F_ + fo] = o;
        }
    }
}

extern "C" void kernel_launch(void* const* d_in, const int* in_sizes, int n_in,
                              void* d_out, int out_size, void* d_ws, size_t ws_size,
                              hipStream_t stream) {
    const float* x = (const float*)d_in[0];       // [2,48,48,48,4]
    const float* w = (const float*)d_in[1];       // [4,16,3,4]
    const float* w_cp = (const float*)d_in[2];    // [4,16]
    const float* b_cp = (const float*)d_in[3];    // [16]
    const float* bias = (const float*)d_in[4];    // [64]
    const float* w_proj = (const float*)d_in[5];  // [64,16]
    const float* b_proj = (const float*)d_in[6];  // [16]
    float* out = (float*)d_out;                   // [2,48,48,48,16]
    f16* efb = (f16*)d_ws;                        // 131072 f16 (256 KB)

    build_filters<<<512, 256, 0, stream>>>(w, efb);
    sshconv_main<<<3456, 256, 0, stream>>>(x, efb, w_cp, b_cp, bias, w_proj, b_proj, out);
}

// Round 3
// 69.880 us; speedup vs baseline: 12.2491x; 1.6622x over previous
//
#include <hip/hip_runtime.h>
#include <math.h>

typedef _Float16 f16;
typedef _Float16 f16x2 __attribute__((ext_vector_type(2)));
typedef _Float16 f16x4 __attribute__((ext_vector_type(4)));
typedef _Float16 f16x8 __attribute__((ext_vector_type(8)));
typedef float f32x4 __attribute__((ext_vector_type(4)));

#define NVOX 48
#define F_ 16

// ---------------------------------------------------------------------------
// Kernel 1: build effective filter bank directly in MFMA-B fragment layout.
// efb[kq(64)][n(256)][j(8)] f16, where K index k = kq*8+j = tap*4 + c,
// n = f*16 + map. Taps 125..127 are zero-pad. Folds radial shells, the
// degree-shared weights w, and sqrt((m>0?2:1)/(2n+1)) power-spectrum scale.
// ---------------------------------------------------------------------------
__global__ void build_filters(const float* __restrict__ w, f16* __restrict__ efb) {
    int e = blockIdx.x * 256 + threadIdx.x;  // 0..131071
    int j = e & 7;
    int n = (e >> 3) & 255;
    int kq = e >> 11;            // 0..63
    int k = kq * 8 + j;          // 0..511
    int tap = k >> 2, c = k & 3, f = n >> 4, map = n & 15;

    float outv = 0.f;
    if (tap < 125) {
        int fd = tap / 25, fh = (tap / 5) % 5, fw = tap % 5;
        // meshgrid(indexing='xy'): x = g[fh], y = g[fd], z = g[fw]
        float xx = (float)(fh - 2), yy = (float)(fd - 2), zz = (float)(fw - 2);
        float r = sqrtf(xx * xx + yy * yy + zz * zz);
        float rxy = sqrtf(xx * xx + yy * yy);
        float ct = (r > 0.f) ? zz / r : 0.f;
        float st = sqrtf(fmaxf(0.f, 1.f - ct * ct));
        float cp = (rxy > 0.f) ? xx / rxy : 1.f;
        float sp = (rxy > 0.f) ? yy / rxy : 0.f;
        float c2p = cp * cp - sp * sp, s2p = 2.f * cp * sp;
        float c3p = c2p * cp - s2p * sp, s3p = s2p * cp + c2p * sp;

        const float k00 = 0.28209479177387814f;
        const float k10 = 0.48860251190291992f;
        const float c1v = 0.34549414947133547f;
        const float k20 = 0.31539156525252005f;
        const float c21 = 0.77254840404637908f;
        const float c22 = 0.38627420202318954f;
        const float k30 = 0.37317633259011546f;
        const float c31 = 0.32318018411415065f;
        const float c32 = 1.02198547643328236f;
        const float c33 = 0.41722382363278409f;

        float val;
        int deg;
        switch (map) {
            case 0:  deg = 0; val = k00; break;
            case 1:  deg = 1; val = k10 * ct; break;
            case 2:  deg = 1; val = -c1v * st * cp; break;
            case 3:  deg = 1; val = -c1v * st * sp; break;
            case 4:  deg = 2; val = k20 * (3.f * ct * ct - 1.f); break;
            case 5:  deg = 2; val = -c21 * st * ct * cp; break;
            case 6:  deg = 2; val = -c21 * st * ct * sp; break;
            case 7:  deg = 2; val = c22 * st * st * c2p; break;
            case 8:  deg = 2; val = c22 * st * st * s2p; break;
            case 9:  deg = 3; val = k30 * (5.f * ct * ct * ct - 3.f * ct); break;
            case 10: deg = 3; val = -c31 * st * (5.f * ct * ct - 1.f) * cp; break;
            case 11: deg = 3; val = -c31 * st * (5.f * ct * ct - 1.f) * sp; break;
            case 12: deg = 3; val = c32 * st * st * ct * c2p; break;
            case 13: deg = 3; val = c32 * st * st * ct * s2p; break;
            case 14: deg = 3; val = -c33 * st * st * st * c3p; break;
            default: deg = 3; val = -c33 * st * st * st * s3p; break;
        }
        const float scale_tab[16] = {
            1.f,
            0.57735026918962576f, 0.81649658092772603f, 0.81649658092772603f,
            0.44721359549995794f, 0.63245553203367587f, 0.63245553203367587f,
            0.63245553203367587f, 0.63245553203367587f,
            0.37796447300922720f, 0.53452248382484879f, 0.53452248382484879f,
            0.53452248382484879f, 0.53452248382484879f, 0.53452248382484879f,
            0.53452248382484879f};

        float wsum = 0.f;
#pragma unroll
        for (int i = 0; i < 3; ++i) {
            float rad = fmaxf(0.f, 1.f - fabsf(r - (float)i));
            wsum += rad * w[((c * F_ + f) * 3 + i) * 4 + deg];
        }
        outv = wsum * val * scale_tab[map];
    }
    efb[e] = (f16)outv;
}

// ---------------------------------------------------------------------------
// Kernel 2: MFMA main kernel.
// Block = 256 threads = 4 waves. Tile: M=64 voxels (4x4x4), N=256 (16f x 16maps).
// Wave wv owns n in [wv*64, wv*64+64). K = 512 (128 taps x 4 ch, taps>=125 zero).
// Epilogue: quarter-wise acc->mapsQ (b128), float4 read + square + fp16 packed
// partials, combine + central + signed-log -> s16 (fp16), projection via MFMA.
// ---------------------------------------------------------------------------
__global__ __launch_bounds__(256, 4) void sshconv_main(
    const float* __restrict__ x, const f16* __restrict__ efb,
    const float* __restrict__ w_cp, const float* __restrict__ b_cp,
    const float* __restrict__ bias, const float* __restrict__ w_proj,
    const float* __restrict__ b_proj, float* __restrict__ out) {
    __shared__ f16 xs[2048];            // 8x8x8 voxels x 4ch fp16 (4 KB)
    __shared__ int off_tab[128];        // tap -> element offset in xs
    __shared__ float mapsQ[16 * 324];   // [f][m*20 + vox16], padded (20.7 KB)
    __shared__ f16x2 part2h[16 * 64];   // packed (pa,pb) partials (4 KB)
    __shared__ f16 s16[64 * 72];        // s values, [vox64][72pad] (9.2 KB)

    const int tid = threadIdx.x;
    const int bt = blockIdx.x;
    const int tw = bt % 12, th = (bt / 12) % 12, td = (bt / 144) % 12, b = bt / 1728;
    const int d0 = td * 4, h0 = th * 4, w0 = tw * 4;

    if (tid < 128) {
        int t = tid;
        off_tab[t] = (t < 125) ? (t / 25) * 64 + ((t / 5) % 5) * 8 + (t % 5) : 0;
    }

    // stage x tile (zero halo), fp32 -> fp16
#pragma unroll
    for (int i = 0; i < 2; ++i) {
        int s = tid * 2 + i;  // 0..511
        int sd = s >> 6, sh = (s >> 3) & 7, sw = s & 7;
        int gd = d0 - 2 + sd, gh = h0 - 2 + sh, gw = w0 - 2 + sw;
        float4 v = make_float4(0.f, 0.f, 0.f, 0.f);
        if (gd >= 0 && gd < NVOX && gh >= 0 && gh < NVOX && gw >= 0 && gw < NVOX)
            v = *(const float4*)&x[(((b * NVOX + gd) * NVOX + gh) * NVOX + gw) * 4];
        f16x4 hv = {(f16)v.x, (f16)v.y, (f16)v.z, (f16)v.w};
        *(f16x4*)&xs[s * 4] = hv;
    }
    __syncthreads();

    const int lane = tid & 63, wv = tid >> 6;
    const int col = lane & 15, ksel = lane >> 4;   // A-row voxel / K sub-group
    const int vh = col >> 2, vw = col & 3;
    const int abase = vh * 8 + vw;

    f32x4 acc[4][4];  // [mf][nb]
#pragma unroll
    for (int m = 0; m < 4; ++m)
#pragma unroll
        for (int nbi = 0; nbi < 4; ++nbi) acc[m][nbi] = (f32x4){0.f, 0.f, 0.f, 0.f};

    const f16* bptr = efb + ((ksel * 256) + wv * 64 + col) * 8;

#pragma unroll 2
    for (int kblk = 0; kblk < 16; ++kblk) {
        const int t0 = kblk * 8 + ksel * 2;
        const int o0 = off_tab[t0], o1 = off_tab[t0 + 1];

        f16x8 a[4];
#pragma unroll
        for (int mf = 0; mf < 4; ++mf) {
            f16x4 lo = *(const f16x4*)&xs[(abase + mf * 64 + o0) * 4];
            f16x4 hi = *(const f16x4*)&xs[(abase + mf * 64 + o1) * 4];
            a[mf] = __builtin_shufflevector(lo, hi, 0, 1, 2, 3, 4, 5, 6, 7);
        }
        f16x8 bf[4];
#pragma unroll
        for (int nb = 0; nb < 4; ++nb)
            bf[nb] = *(const f16x8*)(bptr + kblk * 8192 + nb * 128);
#pragma unroll
        for (int nb = 0; nb < 4; ++nb)
#pragma unroll
            for (int mf = 0; mf < 4; ++mf)
                acc[mf][nb] = __builtin_amdgcn_mfma_f32_16x16x32_f16(
                    a[mf], bf[nb], acc[mf][nb], 0, 0, 0);
    }

    // ---- epilogue ----
    const int f_c = tid & 15;          // f for phases B/C
    const int vq_b = (tid >> 4) & 3;   // vox-quad for phase B
    const int mg = tid >> 6;           // map-group (wave) for phase B
    const int vox16_c = tid >> 4;      // vox-in-quarter for phase C
    const int xorf = (f_c & 7) << 2;   // part2h bank swizzle

    const float bpc = b_cp[f_c];
    float wcp0 = w_cp[0 * F_ + f_c], wcp1 = w_cp[1 * F_ + f_c];
    float wcp2 = w_cp[2 * F_ + f_c], wcp3 = w_cp[3 * F_ + f_c];
    const f32x4 bias4 = *(const f32x4*)&bias[f_c * 4];

#pragma unroll
    for (int q = 0; q < 4; ++q) {
        // A: acc quarter -> mapsQ  (vector writes along vox)
#pragma unroll
        for (int nb = 0; nb < 4; ++nb)
            *(f32x4*)&mapsQ[(wv * 4 + nb) * 324 + col * 20 + ksel * 4] = acc[q][nb];
        __syncthreads();
        // B: float4 reads along vox, square, degree partials -> part2h (fp16x2)
        {
            f32x4 mv[4];
#pragma unroll
            for (int m4 = 0; m4 < 4; ++m4)
                mv[m4] = *(const f32x4*)&mapsQ[f_c * 324 + (mg * 4 + m4) * 20 + vq_b * 4];
#pragma unroll
            for (int v = 0; v < 4; ++v) {
                float x0 = mv[0][v], x1 = mv[1][v], x2 = mv[2][v], x3 = mv[3][v];
                float pa, pb;
                if (mg == 0)      { pa = x0;                                  pb = x1 * x1 + x2 * x2 + x3 * x3; }
                else if (mg == 1) { pa = x0 * x0 + x1 * x1 + x2 * x2 + x3 * x3; pb = 0.f; }
                else if (mg == 2) { pa = x0 * x0;                             pb = x1 * x1 + x2 * x2 + x3 * x3; }
                else              { pa = x0 * x0 + x1 * x1 + x2 * x2 + x3 * x3; pb = 0.f; }
                int o = (vq_b * 16 + v * 4 + mg) ^ xorf;
                part2h[f_c * 64 + o] = (f16x2){(f16)pa, (f16)pb};
            }
        }
        __syncthreads();
        // C: combine partials + central + bias + signed-log -> s16
        {
            const int vhh = vox16_c >> 2, vww = vox16_c & 3;
            const int ob = (vox16_c * 4) ^ xorf;   // vq*16+v*4 == vox16*4
            f16x8 pr = *(const f16x8*)&part2h[f_c * 64 + ob];
            f16x4 xc = *(const f16x4*)&xs[((q + 2) * 64 + (vhh + 2) * 8 + (vww + 2)) * 4];
            float cen = bpc + (float)xc[0] * wcp0 + (float)xc[1] * wcp1 +
                        (float)xc[2] * wcp2 + (float)xc[3] * wcp3;
            float s0 = (float)pr[0] + cen;
            s0 = s0 * s0;
            f32x4 sv = {s0, (float)pr[1], (float)pr[2] + (float)pr[4],
                        (float)pr[5] + (float)pr[6]};
            f16 so[4];
#pragma unroll
            for (int n = 0; n < 4; ++n) {
                float vb = sv[n] + bias4[n];
                float lg = __builtin_amdgcn_logf(1.f + fabsf(vb)) * 0.69314718055994531f;
                so[n] = (f16)copysignf(lg, vb);
            }
            *(f16x4*)&s16[(q * 16 + vox16_c) * 72 + f_c * 4] = *(f16x4*)so;
        }
        // no barrier needed: next A writes mapsQ (B readers done), C's part2h
        // reads complete before next B's writes (barrier after next A).
    }

    // ---- projection via MFMA: s16[64][64] x w_proj[64][16] ----
    const int fo = lane & 15, kg = lane >> 4;
    f16 wb0[8], wb1[8];
#pragma unroll
    for (int j = 0; j < 8; ++j) {
        wb0[j] = (f16)w_proj[(kg * 8 + j) * F_ + fo];
        wb1[j] = (f16)w_proj[(32 + kg * 8 + j) * F_ + fo];
    }
    const float bpj = b_proj[fo];
    __syncthreads();

    f16x8 a0 = *(const f16x8*)&s16[(wv * 16 + col) * 72 + kg * 8];
    f16x8 a1 = *(const f16x8*)&s16[(wv * 16 + col) * 72 + 32 + kg * 8];
    f32x4 oc = {0.f, 0.f, 0.f, 0.f};
    oc = __builtin_amdgcn_mfma_f32_16x16x32_f16(a0, *(f16x8*)wb0, oc, 0, 0, 0);
    oc = __builtin_amdgcn_mfma_f32_16x16x32_f16(a1, *(f16x8*)wb1, oc, 0, 0, 0);

#pragma unroll
    for (int r = 0; r < 4; ++r) {
        float o = fmaxf(oc[r] + bpj, 0.f);
        out[(((b * NVOX + d0 + wv) * NVOX + h0 + kg) * NVOX + w0 + r) * F_ + fo] = o;
    }
}

extern "C" void kernel_launch(void* const* d_in, const int* in_sizes, int n_in,
                              void* d_out, int out_size, void* d_ws, size_t ws_size,
                              hipStream_t stream) {
    const float* x = (const float*)d_in[0];       // [2,48,48,48,4]
    const float* w = (const float*)d_in[1];       // [4,16,3,4]
    const float* w_cp = (const float*)d_in[2];    // [4,16]
    const float* b_cp = (const float*)d_in[3];    // [16]
    const float* bias = (const float*)d_in[4];    // [64]
    const float* w_proj = (const float*)d_in[5];  // [64,16]
    const float* b_proj = (const float*)d_in[6];  // [16]
    float* out = (float*)d_out;                   // [2,48,48,48,16]
    f16* efb = (f16*)d_ws;                        // 131072 f16 (256 KB)

    build_filters<<<512, 256, 0, stream>>>(w, efb);
    sshconv_main<<<3456, 256, 0, stream>>>(x, efb, w_cp, b_cp, bias, w_proj, b_proj, out);
}

// Round 4
// 64.371 us; speedup vs baseline: 13.2975x; 1.0856x over previous
//
#include <hip/hip_runtime.h>
#include <math.h>

typedef _Float16 f16;
typedef _Float16 f16x2 __attribute__((ext_vector_type(2)));
typedef _Float16 f16x4 __attribute__((ext_vector_type(4)));
typedef _Float16 f16x8 __attribute__((ext_vector_type(8)));
typedef float f32x4 __attribute__((ext_vector_type(4)));

#define NVOX 48
#define F_ 16

// ---------------------------------------------------------------------------
// Kernel 1: build effective filter bank in MFMA fragment layout.
// efb[kq(64)][n(256)][j(8)] f16, K index k = kq*8+j = tap*4 + c, n = f*16+map.
// Taps 125..127 zero-pad. Folds radial shells, degree-shared w, and
// sqrt((m>0?2:1)/(2n+1)) power-spectrum scale.
// ---------------------------------------------------------------------------
__global__ void build_filters(const float* __restrict__ w, f16* __restrict__ efb) {
    int e = blockIdx.x * 256 + threadIdx.x;  // 0..131071
    int j = e & 7;
    int n = (e >> 3) & 255;
    int kq = e >> 11;            // 0..63
    int k = kq * 8 + j;          // 0..511
    int tap = k >> 2, c = k & 3, f = n >> 4, map = n & 15;

    float outv = 0.f;
    if (tap < 125) {
        int fd = tap / 25, fh = (tap / 5) % 5, fw = tap % 5;
        // meshgrid(indexing='xy'): x = g[fh], y = g[fd], z = g[fw]
        float xx = (float)(fh - 2), yy = (float)(fd - 2), zz = (float)(fw - 2);
        float r = sqrtf(xx * xx + yy * yy + zz * zz);
        float rxy = sqrtf(xx * xx + yy * yy);
        float ct = (r > 0.f) ? zz / r : 0.f;
        float st = sqrtf(fmaxf(0.f, 1.f - ct * ct));
        float cp = (rxy > 0.f) ? xx / rxy : 1.f;
        float sp = (rxy > 0.f) ? yy / rxy : 0.f;
        float c2p = cp * cp - sp * sp, s2p = 2.f * cp * sp;
        float c3p = c2p * cp - s2p * sp, s3p = s2p * cp + c2p * sp;

        const float k00 = 0.28209479177387814f;
        const float k10 = 0.48860251190291992f;
        const float c1v = 0.34549414947133547f;
        const float k20 = 0.31539156525252005f;
        const float c21 = 0.77254840404637908f;
        const float c22 = 0.38627420202318954f;
        const float k30 = 0.37317633259011546f;
        const float c31 = 0.32318018411415065f;
        const float c32 = 1.02198547643328236f;
        const float c33 = 0.41722382363278409f;

        float val;
        int deg;
        switch (map) {
            case 0:  deg = 0; val = k00; break;
            case 1:  deg = 1; val = k10 * ct; break;
            case 2:  deg = 1; val = -c1v * st * cp; break;
            case 3:  deg = 1; val = -c1v * st * sp; break;
            case 4:  deg = 2; val = k20 * (3.f * ct * ct - 1.f); break;
            case 5:  deg = 2; val = -c21 * st * ct * cp; break;
            case 6:  deg = 2; val = -c21 * st * ct * sp; break;
            case 7:  deg = 2; val = c22 * st * st * c2p; break;
            case 8:  deg = 2; val = c22 * st * st * s2p; break;
            case 9:  deg = 3; val = k30 * (5.f * ct * ct * ct - 3.f * ct); break;
            case 10: deg = 3; val = -c31 * st * (5.f * ct * ct - 1.f) * cp; break;
            case 11: deg = 3; val = -c31 * st * (5.f * ct * ct - 1.f) * sp; break;
            case 12: deg = 3; val = c32 * st * st * ct * c2p; break;
            case 13: deg = 3; val = c32 * st * st * ct * s2p; break;
            case 14: deg = 3; val = -c33 * st * st * st * c3p; break;
            default: deg = 3; val = -c33 * st * st * st * s3p; break;
        }
        const float scale_tab[16] = {
            1.f,
            0.57735026918962576f, 0.81649658092772603f, 0.81649658092772603f,
            0.44721359549995794f, 0.63245553203367587f, 0.63245553203367587f,
            0.63245553203367587f, 0.63245553203367587f,
            0.37796447300922720f, 0.53452248382484879f, 0.53452248382484879f,
            0.53452248382484879f, 0.53452248382484879f, 0.53452248382484879f,
            0.53452248382484879f};

        float wsum = 0.f;
#pragma unroll
        for (int i = 0; i < 3; ++i) {
            float rad = fmaxf(0.f, 1.f - fabsf(r - (float)i));
            wsum += rad * w[((c * F_ + f) * 3 + i) * 4 + deg];
        }
        outv = wsum * val * scale_tab[map];
    }
    efb[e] = (f16)outv;
}

// ---------------------------------------------------------------------------
// Kernel 2: MFMA main kernel with SWAPPED operands: mfma(filters, voxels, acc)
// -> D[n_row][vox_col]: lane holds maps ksel*4..+3 (per-degree groups align
// with ksel quads) for voxel vb*16+col. Power-spectrum partials computed
// IN-REGISTER, one small XOR-swizzled f16x2 LDS pass, then projection MFMA.
// ---------------------------------------------------------------------------
__global__ __launch_bounds__(256, 4) void sshconv_main(
    const float* __restrict__ x, const f16* __restrict__ efb,
    const float* __restrict__ w_cp, const float* __restrict__ b_cp,
    const float* __restrict__ bias, const float* __restrict__ w_proj,
    const float* __restrict__ b_proj, float* __restrict__ out) {
    __shared__ f16 xs[2048];            // 8x8x8 voxels x 4ch fp16 (4 KB)
    __shared__ int off_tab[128];        // tap -> element offset in xs
    __shared__ f16x2 part2[16 * 64 * 4];// [f][vox][ksel^f&3] (pa,pb) (16 KB)
    __shared__ f16 s16[64 * 72];        // s values, [vox64][72pad] (9.2 KB)

    const int tid = threadIdx.x;
    const int bt = blockIdx.x;
    const int tw = bt % 12, th = (bt / 12) % 12, td = (bt / 144) % 12, b = bt / 1728;
    const int d0 = td * 4, h0 = th * 4, w0 = tw * 4;

    if (tid < 128) {
        int t = tid;
        off_tab[t] = (t < 125) ? (t / 25) * 64 + ((t / 5) % 5) * 8 + (t % 5) : 0;
    }

    // stage x tile (zero halo), fp32 -> fp16
#pragma unroll
    for (int i = 0; i < 2; ++i) {
        int s = tid * 2 + i;  // 0..511
        int sd = s >> 6, sh = (s >> 3) & 7, sw = s & 7;
        int gd = d0 - 2 + sd, gh = h0 - 2 + sh, gw = w0 - 2 + sw;
        float4 v = make_float4(0.f, 0.f, 0.f, 0.f);
        if (gd >= 0 && gd < NVOX && gh >= 0 && gh < NVOX && gw >= 0 && gw < NVOX)
            v = *(const float4*)&x[(((b * NVOX + gd) * NVOX + gh) * NVOX + gw) * 4];
        f16x4 hv = {(f16)v.x, (f16)v.y, (f16)v.z, (f16)v.w};
        *(f16x4*)&xs[s * 4] = hv;
    }
    __syncthreads();

    const int lane = tid & 63, wv = tid >> 6;
    const int col = lane & 15, ksel = lane >> 4;
    const int vh = col >> 2, vw = col & 3;
    const int abase = vh * 8 + vw;

    f32x4 acc[4][4];  // [nf][vb]
#pragma unroll
    for (int i = 0; i < 4; ++i)
#pragma unroll
        for (int jj = 0; jj < 4; ++jj) acc[i][jj] = (f32x4){0.f, 0.f, 0.f, 0.f};

    const f16* bptr = efb + ((ksel * 256) + wv * 64 + col) * 8;

#pragma unroll 2
    for (int kblk = 0; kblk < 16; ++kblk) {
        const int t0 = kblk * 8 + ksel * 2;
        const int o0 = off_tab[t0], o1 = off_tab[t0 + 1];

        f16x8 a[4];  // voxel fragments (B operand), vb = voxel subtile
#pragma unroll
        for (int vb = 0; vb < 4; ++vb) {
            f16x4 lo = *(const f16x4*)&xs[(abase + vb * 64 + o0) * 4];
            f16x4 hi = *(const f16x4*)&xs[(abase + vb * 64 + o1) * 4];
            a[vb] = __builtin_shufflevector(lo, hi, 0, 1, 2, 3, 4, 5, 6, 7);
        }
        f16x8 bf[4];  // filter fragments (A operand), nf = n subtile (f)
#pragma unroll
        for (int nf = 0; nf < 4; ++nf)
            bf[nf] = *(const f16x8*)(bptr + kblk * 8192 + nf * 128);
#pragma unroll
        for (int nf = 0; nf < 4; ++nf)
#pragma unroll
            for (int vb = 0; vb < 4; ++vb)
                acc[nf][vb] = __builtin_amdgcn_mfma_f32_16x16x32_f16(
                    bf[nf], a[vb], acc[nf][vb], 0, 0, 0);
    }

    // ---- in-register power-spectrum partials -> part2 ----
    float wcp[4][4], bcp[4];
#pragma unroll
    for (int nf = 0; nf < 4; ++nf) {
        const int f = wv * 4 + nf;
        bcp[nf] = b_cp[f];
#pragma unroll
        for (int c = 0; c < 4; ++c) wcp[nf][c] = w_cp[c * F_ + f];
    }

#pragma unroll
    for (int vb = 0; vb < 4; ++vb) {
        f16x4 xc = *(const f16x4*)&xs[((vb + 2) * 64 + (vh + 2) * 8 + (vw + 2)) * 4];
        const float xc0 = (float)xc[0], xc1 = (float)xc[1];
        const float xc2 = (float)xc[2], xc3 = (float)xc[3];
        const int vox = vb * 16 + col;
#pragma unroll
        for (int nf = 0; nf < 4; ++nf) {
            const f32x4 v = acc[nf][vb];
            float cen = bcp[nf] + xc0 * wcp[nf][0] + xc1 * wcp[nf][1] +
                        xc2 * wcp[nf][2] + xc3 * wcp[nf][3];
            float v0 = v[0] + ((ksel == 0) ? cen : 0.f);
            float s0 = v0 * v0, s1 = v[1] * v[1], s2 = v[2] * v[2], s3 = v[3] * v[3];
            float pa = (ksel & 1) ? (s0 + s1) : s0;
            float pb = (ksel & 1) ? (s2 + s3) : (s1 + s2 + s3);
            const int f = wv * 4 + nf;
            part2[(f * 64 + vox) * 4 + (ksel ^ (f & 3))] = (f16x2){(f16)pa, (f16)pb};
        }
    }
    __syncthreads();

    // ---- combine partials + bias + signed-log -> s16 ----
    {
        const int fc = tid >> 4, vlo = tid & 15;
        const int kx = fc & 3;
        const f32x4 bias4 = *(const f32x4*)&bias[fc * 4];
#pragma unroll
        for (int it = 0; it < 4; ++it) {
            const int vox = it * 16 + vlo;
            const int base = (fc * 64 + vox) * 4;
            f16x2 p0 = part2[base + (0 ^ kx)];
            f16x2 p1 = part2[base + (1 ^ kx)];
            f16x2 p2 = part2[base + (2 ^ kx)];
            f16x2 p3 = part2[base + (3 ^ kx)];
            f32x4 sv = {(float)p0[0], (float)p0[1],
                        (float)p1[0] + (float)p1[1] + (float)p2[0],
                        (float)p2[1] + (float)p3[0] + (float)p3[1]};
            f16 so[4];
#pragma unroll
            for (int n = 0; n < 4; ++n) {
                float vb2 = sv[n] + bias4[n];
                float lg = __builtin_amdgcn_logf(1.f + fabsf(vb2)) * 0.69314718055994531f;
                so[n] = (f16)copysignf(lg, vb2);
            }
            *(f16x4*)&s16[vox * 72 + fc * 4] = *(f16x4*)so;
        }
    }

    // ---- projection via MFMA: s16[64][64] x w_proj[64][16] ----
    const int fo = lane & 15, kg = lane >> 4;
    f16 wb0[8], wb1[8];
#pragma unroll
    for (int j = 0; j < 8; ++j) {
        wb0[j] = (f16)w_proj[(kg * 8 + j) * F_ + fo];
        wb1[j] = (f16)w_proj[(32 + kg * 8 + j) * F_ + fo];
    }
    const float bpj = b_proj[fo];
    __syncthreads();

    f16x8 a0 = *(const f16x8*)&s16[(wv * 16 + col) * 72 + kg * 8];
    f16x8 a1 = *(const f16x8*)&s16[(wv * 16 + col) * 72 + 32 + kg * 8];
    f32x4 oc = {0.f, 0.f, 0.f, 0.f};
    oc = __builtin_amdgcn_mfma_f32_16x16x32_f16(a0, *(f16x8*)wb0, oc, 0, 0, 0);
    oc = __builtin_amdgcn_mfma_f32_16x16x32_f16(a1, *(f16x8*)wb1, oc, 0, 0, 0);

#pragma unroll
    for (int r = 0; r < 4; ++r) {
        float o = fmaxf(oc[r] + bpj, 0.f);
        out[(((b * NVOX + d0 + wv) * NVOX + h0 + kg) * NVOX + w0 + r) * F_ + fo] = o;
    }
}

extern "C" void kernel_launch(void* const* d_in, const int* in_sizes, int n_in,
                              void* d_out, int out_size, void* d_ws, size_t ws_size,
                              hipStream_t stream) {
    const float* x = (const float*)d_in[0];       // [2,48,48,48,4]
    const float* w = (const float*)d_in[1];       // [4,16,3,4]
    const float* w_cp = (const float*)d_in[2];    // [4,16]
    const float* b_cp = (const float*)d_in[3];    // [16]
    const float* bias = (const float*)d_in[4];    // [64]
    const float* w_proj = (const float*)d_in[5];  // [64,16]
    const float* b_proj = (const float*)d_in[6];  // [16]
    float* out = (float*)d_out;                   // [2,48,48,48,16]
    f16* efb = (f16*)d_ws;                        // 131072 f16 (256 KB)

    build_filters<<<512, 256, 0, stream>>>(w, efb);
    sshconv_main<<<3456, 256, 0, stream>>>(x, efb, w_cp, b_cp, bias, w_proj, b_proj, out);
}